// Round 8
// baseline (550.164 us; speedup 1.0000x reference)
//
#include <hip/hip_runtime.h>
#include <hip/hip_bf16.h>

typedef __bf16 bf16;
typedef __bf16 bf16x8 __attribute__((ext_vector_type(8)));
typedef float  f32x4  __attribute__((ext_vector_type(4)));

static constexpr int NB  = 16;
static constexpr int NN  = 2048;
static constexpr int HID = 128;

// async 16B global -> LDS. LDS dest is wave-uniform base (+ lane*16 in HW);
// global src address IS per-lane (must carry the lane term!).
__device__ __forceinline__ void gload_lds16(const bf16* g, bf16* l) {
    __builtin_amdgcn_global_load_lds(
        (const __attribute__((address_space(1))) unsigned int*)g,
        (__attribute__((address_space(3))) unsigned int*)l, 16, 0, 0);
}

#define WAITV(n) asm volatile("s_waitcnt vmcnt(" #n ")" ::: "memory")

// ---------------------------------------------------------------------------
// Tiled layouts (16B chunks):
//  A-tile (32 rows x 64 k, 4 KB, 256 ch): ch = r*8 + (kc ^ (r&7)), kc = k/8.
//    adjT: [b][mt(64)][kk(32)][256 ch].
//  B-tile (128 n x 64 k, 16 KB, 1024 ch): ch = n*8 + (kc ^ (n&7)).
//    xTt/hT: [b][kk(32)][1024 ch]   (kk = source-node block of 64).
//  WTg per layer (32 KB, 2048 ch): ch = n*16 + half*8 + (kc8 ^ (n&7)),
//    half = k>>6, kc8 = (k&63)>>3   (k-contig bf16x8 frags of W^T[n][k]).
// ---------------------------------------------------------------------------

// prep: W (128x128 fp32, [k][n]) -> swizzled WT tiles, for all 3 layers
__global__ __launch_bounds__(256) void prep_wt(const float* __restrict__ W0,
                                               const float* __restrict__ W1,
                                               const float* __restrict__ W2,
                                               bf16* __restrict__ WTg) {
    int l = blockIdx.x;
    const float* W = (l == 0) ? W0 : (l == 1) ? W1 : W2;
    bf16* out = WTg + l * 16384;
    int tid = threadIdx.x;
#pragma unroll
    for (int i = 0; i < 8; ++i) {
        int p = i * 256 + tid;                 // [0,2048)
        int n = p >> 4, half = (p >> 3) & 1, cs = p & 7;
        int kc = cs ^ (n & 7);
        int kbase = half * 64 + kc * 8;
        bf16x8 o;
#pragma unroll
        for (int r = 0; r < 8; ++r) o[r] = (bf16)W[(kbase + r) * 128 + n];
        *(bf16x8*)(out + p * 8) = o;
    }
}

// prep: x (16,2048,128) fp32 -> xTt tiled bf16 B-tiles
__global__ __launch_bounds__(256) void prep_xt(const float* __restrict__ x,
                                               bf16* __restrict__ xTt) {
    __shared__ bf16 T[128 * 136];
    const int blk = blockIdx.x;            // 256 blocks: 16 node-tiles x 16 b
    const int b = blk >> 4, node0 = (blk & 15) * 128;
    const int tid = threadIdx.x;
    const float* xb = x + ((size_t)b * NN + node0) * HID;
#pragma unroll
    for (int i = 0; i < 64; ++i) {
        int idx = i * 256 + tid;
        int node = idx >> 7, hid = idx & 127;
        T[hid * 136 + node] = (bf16)xb[(size_t)node * HID + hid];
    }
    __syncthreads();
#pragma unroll
    for (int i = 0; i < 8; ++i) {
        int p = i * 256 + tid;                 // [0,2048) chunks (2 tiles)
        int half = p >> 10, p1 = p & 1023;
        int n = p1 >> 3, cs = p1 & 7, c = cs ^ (n & 7), m = half * 64 + c * 8;
        *(bf16x8*)(xTt + ((size_t)b * 32 + (node0 >> 6) + half) * 8192 + p1 * 8)
            = *(const bf16x8*)(T + n * 136 + m);
    }
}

// ---------------------------------------------------------------------------
// layer: g = adj[b](32-row slab) @ h[b]; then h' = relu(LN(g@W + bias)).
// BM=32, BN=128, BK=64, 32 K-steps, 2 waves/block, grid 1024.
// LDS dbuf 2 x (4KB A + 16KB B) = 40 KB -> 4 INDEPENDENT blocks/CU.
// R3-proven schedule: counted vmcnt + 2 barriers/step, stage kk+2 after
// reader barrier.  W-frags from global in epilogue (L2-resident).
// AMODE 1: A from fp32 adj (coalesced) -> regs -> cvt -> ds_write + adjT
//          side-write; __syncthreads pipeline (HBM-bound anyway).
// AMODE 2: A via linear gload_lds from adjT.
// ---------------------------------------------------------------------------
template<int AMODE, bool FINAL>
__global__ __launch_bounds__(128, 2) void layer32(
        const float* __restrict__ Af, bf16* __restrict__ adjT,
        const bf16* __restrict__ Bt, const bf16* __restrict__ WTg,
        const float* __restrict__ bias, const float* __restrict__ gam,
        const float* __restrict__ bet, bf16* __restrict__ hOut,
        float* __restrict__ outF) {
    __shared__ __align__(16) bf16 lds[20480];   // 2 bufs x 10240 elems (A 2048 + B 8192)

    const int tid = threadIdx.x, wave = tid >> 6, lane = tid & 63;
    const int c0 = lane & 15, q = lane >> 4;
    const int blk = blockIdx.x, xcd = blk & 7, jj = blk >> 3;
    const int b = xcd * 2 + (jj & 1);          // each XCD owns 2 batches
    const int mt = jj >> 1, m0 = mt * 32;      // [0,64) m-tiles of 32 rows

    const bf16* Btb = Bt + (size_t)b * 32 * 8192;
    bf16* Atl = adjT + ((size_t)b * 64 + mt) * (size_t)(32 * 2048);
    const float* Afb = Af + (size_t)b * NN * NN + (size_t)m0 * NN;

    f32x4 acc[8] = {};

    auto stageA = [&](int buf, int kk) {       // 256 ch: 2 gloads/wave
#pragma unroll
        for (int j = 0; j < 2; ++j) {
            int cb = j * 128 + wave * 64;
            gload_lds16(Atl + (size_t)kk * 2048 + (size_t)(cb + lane) * 8,
                        lds + buf * 10240 + cb * 8);
        }
    };
    auto stageB = [&](int buf, int kk) {       // 1024 ch: 8 gloads/wave
#pragma unroll
        for (int j = 0; j < 8; ++j) {
            int cb = j * 128 + wave * 64;
            gload_lds16(Btb + (size_t)kk * 8192 + (size_t)(cb + lane) * 8,
                        lds + buf * 10240 + 2048 + cb * 8);
        }
    };
    auto compute = [&](int buf) {
        const bf16* As = lds + buf * 10240;
        const bf16* Bs = As + 2048;
#pragma unroll
        for (int ks = 0; ks < 2; ++ks) {
            int kb = ks * 4 + q;
            int ar = wave * 16 + c0;           // [0,32)
            bf16x8 af = *(const bf16x8*)(As + ar * 64 + (kb ^ (ar & 7)) * 8);
#pragma unroll
            for (int nt = 0; nt < 8; ++nt) {
                int br = nt * 16 + c0;
                bf16x8 bw = *(const bf16x8*)(Bs + br * 64 + (kb ^ (br & 7)) * 8);
                acc[nt] = __builtin_amdgcn_mfma_f32_16x16x32_bf16(af, bw, acc[nt], 0, 0, 0);
            }
        }
    };

    if constexpr (AMODE == 1) {
        int grow[2], gcb[2];
#pragma unroll
        for (int j = 0; j < 2; ++j) {
            int gi = j * 128 + tid;
            grow[j] = gi >> 3; gcb[j] = gi & 7;   // 8 thr/row, rows 0..31
        }
        f32x4 va[2], vb[2];
        auto loadA = [&](int kk) {
#pragma unroll
            for (int j = 0; j < 2; ++j) {
                const float* s = Afb + (size_t)grow[j] * NN + kk * 64 + gcb[j] * 8;
                va[j] = *(const f32x4*)s;
                vb[j] = *(const f32x4*)(s + 4);
            }
        };
        auto writeA = [&](int buf, int kk) {
#pragma unroll
            for (int j = 0; j < 2; ++j) {
                bf16x8 o = {(bf16)va[j].x, (bf16)va[j].y, (bf16)va[j].z, (bf16)va[j].w,
                            (bf16)vb[j].x, (bf16)vb[j].y, (bf16)vb[j].z, (bf16)vb[j].w};
                int ch = grow[j] * 8 + (gcb[j] ^ (grow[j] & 7));
                *(bf16x8*)(lds + buf * 10240 + ch * 8) = o;
                *(bf16x8*)(Atl + (size_t)kk * 2048 + ch * 8) = o;  // tiled side-write
            }
        };
        loadA(0); stageB(0, 0); writeA(0, 0);
        __syncthreads();
        int cur = 0;
        for (int kk = 0; kk < 32; ++kk) {
            if (kk < 31) { loadA(kk + 1); stageB(cur ^ 1, kk + 1); }
            compute(cur);
            if (kk < 31) writeA(cur ^ 1, kk + 1);
            __syncthreads();                     // full drain: tile kk+1 ready
            cur ^= 1;
        }
    } else {
        // prologue: tiles 0,1 in flight (10 loads/wave each -> 20)
        stageA(0, 0); stageB(0, 0);
        stageA(1, 1); stageB(1, 1);
#pragma unroll 1
        for (int kk = 0; kk < 32; ++kk) {
            // in-order retirement: tile kk's 10 loads (mine) landed; barrier
            // makes it true for both waves' portions.
            if (kk < 31) WAITV(10);
            else         WAITV(0);
            __builtin_amdgcn_s_barrier();
            asm volatile("" ::: "memory");
            compute(kk & 1);
            asm volatile("" ::: "memory");
            __builtin_amdgcn_s_barrier();        // both waves done reading buf kk&1
            if (kk < 30) { stageA(kk & 1, kk + 2); stageB(kk & 1, kk + 2); }
        }
        __syncthreads();
    }

    // ---- epilogue: g-tile bf16 -> G = lds[0..4352) as [32][136] ----
    bf16* G = lds;
#pragma unroll
    for (int nt = 0; nt < 8; ++nt)
#pragma unroll
        for (int r = 0; r < 4; ++r) {
            int row = wave * 16 + q * 4 + r;     // [0,32)
            G[row * 136 + nt * 16 + c0] = (bf16)acc[nt][r];
        }
    __syncthreads();

    // ---- W-GEMM: h(32x128) = G @ W ; W-frags from global (L2-resident) ----
    f32x4 a2[8] = {};
    {
        const int gr = wave * 16 + c0;           // [0,32)
#pragma unroll
        for (int ks = 0; ks < 4; ++ks) {
            bf16x8 af = *(const bf16x8*)(G + gr * 136 + ks * 32 + q * 8);
#pragma unroll
            for (int nt = 0; nt < 8; ++nt) {
                int n = nt * 16 + c0;
                int ch = n * 16 + (ks >> 1) * 8 + ((((ks & 1) << 2) | q) ^ (n & 7));
                bf16x8 bw = *(const bf16x8*)(WTg + (size_t)ch * 8);
                a2[nt] = __builtin_amdgcn_mfma_f32_16x16x32_bf16(af, bw, a2[nt], 0, 0, 0);
            }
        }
    }

    // ---- bias + LN(over n=128) + ReLU ----
    float bv[8], gv[8], ev[8];
#pragma unroll
    for (int nt = 0; nt < 8; ++nt) {
        int n = nt * 16 + c0;
        bv[nt] = bias[n]; gv[nt] = gam[n]; ev[nt] = bet[n];
    }
    bf16* Cs = lds;   // [128 n][pitch 40] node-minor; aliases G (post-barrier)
    if constexpr (!FINAL) __syncthreads();       // all W-GEMM reads of G done
#pragma unroll
    for (int r = 0; r < 4; ++r) {
        float v[8], s1 = 0.f, s2 = 0.f;
#pragma unroll
        for (int nt = 0; nt < 8; ++nt) {
            float xv = a2[nt][r] + bv[nt];
            v[nt] = xv; s1 += xv; s2 += xv * xv;
        }
#pragma unroll
        for (int off = 1; off < 16; off <<= 1) {
            s1 += __shfl_xor(s1, off);
            s2 += __shfl_xor(s2, off);
        }
        float mu = s1 * (1.f / 128.f);
        float var = s2 * (1.f / 128.f) - mu * mu;
        float rs = rsqrtf(var + 1e-5f);
        int row = wave * 16 + q * 4 + r;         // local node row in [0,32)
        if constexpr (FINAL) {
            size_t ro = ((size_t)b * NN + m0 + row) * HID;
#pragma unroll
            for (int nt = 0; nt < 8; ++nt) {
                float o = fmaxf((v[nt] - mu) * rs * gv[nt] + ev[nt], 0.f);
                outF[ro + nt * 16 + c0] = o;
            }
        } else {
#pragma unroll
            for (int nt = 0; nt < 8; ++nt) {
                float o = fmaxf((v[nt] - mu) * rs * gv[nt] + ev[nt], 0.f);
                Cs[(nt * 16 + c0) * 40 + row] = (bf16)o;
            }
        }
    }
    if constexpr (!FINAL) {
        __syncthreads();
        // write this block's QUARTER B-tile: target tile kkb = mt>>1,
        // kc range [(mt&1)*4, +4).  512 chunks, 4 per thread.
        const int kkb = mt >> 1, kc0 = (mt & 1) * 4;
        bf16* outp = hOut + ((size_t)b * 32 + kkb) * 8192;
#pragma unroll
        for (int i = 0; i < 4; ++i) {
            int idx = i * 128 + tid;             // [0,512)
            int n = idx >> 2, kco = idx & 3;
            int kc = kc0 + kco;
            int chunk = n * 8 + (kc ^ (n & 7));
            *(bf16x8*)(outp + chunk * 8) = *(const bf16x8*)(Cs + n * 40 + kco * 8);
        }
    }
}

// ---------------------------------------------------------------------------
extern "C" void kernel_launch(void* const* d_in, const int* in_sizes, int n_in,
                              void* d_out, int out_size, void* d_ws, size_t ws_size,
                              hipStream_t stream) {
    const float* x   = (const float*)d_in[0];
    const float* adj = (const float*)d_in[1];
    const float* W[3]  = {(const float*)d_in[2],  (const float*)d_in[6],  (const float*)d_in[10]};
    const float* bb[3] = {(const float*)d_in[3],  (const float*)d_in[7],  (const float*)d_in[11]};
    const float* gg[3] = {(const float*)d_in[4],  (const float*)d_in[8],  (const float*)d_in[12]};
    const float* be[3] = {(const float*)d_in[5],  (const float*)d_in[9],  (const float*)d_in[13]};

    char* ws = (char*)d_ws;
    size_t off = 0;
    auto alloc = [&](size_t bytes) {
        char* p = ws + off; off = (off + bytes + 255) & ~(size_t)255; return p;
    };
    bf16* WTg  = (bf16*)alloc((size_t)3 * 16384 * 2);
    bf16* xTt  = (bf16*)alloc((size_t)NB * 32 * 8192 * 2);            // 8 MiB
    bf16* hT0  = (bf16*)alloc((size_t)NB * 32 * 8192 * 2);            // 8 MiB
    bf16* hT1  = (bf16*)alloc((size_t)NB * 32 * 8192 * 2);            // 8 MiB
    bf16* adjT = (bf16*)alloc((size_t)NB * 64 * 32 * 2048 * 2);       // 128 MiB

    float* outF = (float*)d_out;

    prep_wt<<<3, 256, 0, stream>>>(W[0], W[1], W[2], WTg);
    prep_xt<<<256, 256, 0, stream>>>(x, xTt);

    layer32<1, false><<<1024, 128, 0, stream>>>(adj, adjT, xTt, WTg,
                                                bb[0], gg[0], be[0], hT0, nullptr);
    layer32<2, false><<<1024, 128, 0, stream>>>(adj, adjT, hT0, WTg + 16384,
                                                bb[1], gg[1], be[1], hT1, nullptr);
    layer32<2, true ><<<1024, 128, 0, stream>>>(adj, adjT, hT1, WTg + 2 * 16384,
                                                bb[2], gg[2], be[2], nullptr, outF);
}

// Round 9
// 501.070 us; speedup vs baseline: 1.0980x; 1.0980x over previous
//
#include <hip/hip_runtime.h>
#include <hip/hip_bf16.h>

typedef __bf16 bf16;
typedef __bf16 bf16x8 __attribute__((ext_vector_type(8)));
typedef float  f32x4  __attribute__((ext_vector_type(4)));

static constexpr int NB  = 16;
static constexpr int NN  = 2048;
static constexpr int HID = 128;

// async 16B global -> LDS. LDS dest is wave-uniform base (+ lane*16 in HW);
// global src address IS per-lane (must carry the lane term!).
__device__ __forceinline__ void gload_lds16(const bf16* g, bf16* l) {
    __builtin_amdgcn_global_load_lds(
        (const __attribute__((address_space(1))) unsigned int*)g,
        (__attribute__((address_space(3))) unsigned int*)l, 16, 0, 0);
}

#define WAITV(n) asm volatile("s_waitcnt vmcnt(" #n ")" ::: "memory")

// ---------------------------------------------------------------------------
// Tiled layouts ("LDS images", 16 KB tiles of 1024 16B-chunks):
//   A-tile (128 rows x 64 k): chunk p = row*8 + (kc ^ (row&7)), kc = k/8
//   B-tile (128 n   x 64 k): same formula with n as row
//   adjT[b][mtile(16)][kk(32)] tiles ; xTt/hT: [b][kk(32)] tiles
//   WTg per layer: 2048 chunks: chunk = n*16 + half*8 + (kc8 ^ (n&7)),
//     half = k>>6, kc8 = (k&63)>>3  (k-contig bf16x8 fragments of W^T[n][k])
// ---------------------------------------------------------------------------

// prep: W (128x128 fp32, [k][n]) -> swizzled WT tiles, for all 3 layers
__global__ __launch_bounds__(256) void prep_wt(const float* __restrict__ W0,
                                               const float* __restrict__ W1,
                                               const float* __restrict__ W2,
                                               bf16* __restrict__ WTg) {
    int l = blockIdx.x;
    const float* W = (l == 0) ? W0 : (l == 1) ? W1 : W2;
    bf16* out = WTg + l * 16384;
    int tid = threadIdx.x;
#pragma unroll
    for (int i = 0; i < 8; ++i) {
        int p = i * 256 + tid;                 // [0,2048)
        int n = p >> 4, half = (p >> 3) & 1, cs = p & 7;
        int kc = cs ^ (n & 7);
        int kbase = half * 64 + kc * 8;
        bf16x8 o;
#pragma unroll
        for (int r = 0; r < 8; ++r) o[r] = (bf16)W[(kbase + r) * 128 + n];
        *(bf16x8*)(out + p * 8) = o;
    }
}

// prep: x (16,2048,128) fp32 -> xTt tiled bf16 B-tiles
__global__ __launch_bounds__(256) void prep_xt(const float* __restrict__ x,
                                               bf16* __restrict__ xTt) {
    __shared__ bf16 T[128 * 136];
    const int blk = blockIdx.x;            // 256 blocks: 16 node-tiles x 16 b
    const int b = blk >> 4, node0 = (blk & 15) * 128;
    const int tid = threadIdx.x;
    const float* xb = x + ((size_t)b * NN + node0) * HID;
#pragma unroll
    for (int i = 0; i < 64; ++i) {
        int idx = i * 256 + tid;
        int node = idx >> 7, hid = idx & 127;
        T[hid * 136 + node] = (bf16)xb[(size_t)node * HID + hid];
    }
    __syncthreads();
#pragma unroll
    for (int i = 0; i < 8; ++i) {
        int p = i * 256 + tid;                 // [0,2048) chunks (2 tiles)
        int half = p >> 10, p1 = p & 1023;
        int n = p1 >> 3, cs = p1 & 7, c = cs ^ (n & 7), m = half * 64 + c * 8;
        *(bf16x8*)(xTt + ((size_t)b * 32 + (node0 >> 6) + half) * 8192 + p1 * 8)
            = *(const bf16x8*)(T + n * 136 + m);
    }
}

// ---------------------------------------------------------------------------
// Layer 0 (R3 champion, verbatim): BM=128, 8 waves, 2-deep __syncthreads
// pipeline; A from fp32 adj (coalesced) + tiled adjT side-write; WT in LDS.
// ---------------------------------------------------------------------------
__global__ __launch_bounds__(512, 2) void layer0(
        const float* __restrict__ Af, bf16* __restrict__ adjT,
        const bf16* __restrict__ Bt, const bf16* __restrict__ WTg,
        const float* __restrict__ bias, const float* __restrict__ gam,
        const float* __restrict__ bet, bf16* __restrict__ hOut) {
    __shared__ __align__(16) bf16 lds[49152];
    bf16* WTl = lds + 32768;

    const int tid = threadIdx.x, wave = tid >> 6, lane = tid & 63;
    const int c0 = lane & 15, q = lane >> 4;
    const int blk = blockIdx.x, xcd = blk & 7, jj = blk >> 3;
    const int b = xcd * 2 + (jj & 1);
    const int mtile = jj >> 1, m0 = mtile * 128;
    const int wm = wave >> 1, wn = wave & 1;

    const bf16* Btb = Bt + (size_t)b * 32 * 8192;
    bf16* Atl = adjT + ((size_t)b * 16 + mtile) * (size_t)32 * 8192;

    f32x4 acc[2][4] = {};

#pragma unroll
    for (int j = 0; j < 4; ++j) {
        int cb = j * 512 + wave * 64;
        gload_lds16(WTg + (size_t)(cb + lane) * 8, WTl + cb * 8);
    }

    auto stageB2 = [&](int buf, int kk) {
#pragma unroll
        for (int j = 0; j < 2; ++j) {
            int cb = j * 512 + wave * 64;
            gload_lds16(Btb + (size_t)kk * 8192 + (size_t)(cb + lane) * 8,
                        lds + buf * 16384 + 8192 + cb * 8);
        }
    };
    auto compute = [&](int buf) {
        const bf16* As = lds + buf * 16384;
        const bf16* Bs = As + 8192;
#pragma unroll
        for (int ks = 0; ks < 2; ++ks) {
            bf16x8 af[2], bf_[4];
#pragma unroll
            for (int mt = 0; mt < 2; ++mt) {
                int row = wm * 32 + mt * 16 + c0;
                int cb = (ks * 4 + q) ^ (row & 7);
                af[mt] = *(const bf16x8*)(As + row * 64 + cb * 8);
            }
#pragma unroll
            for (int nt = 0; nt < 4; ++nt) {
                int row = wn * 64 + nt * 16 + c0;
                int cb = (ks * 4 + q) ^ (row & 7);
                bf_[nt] = *(const bf16x8*)(Bs + row * 64 + cb * 8);
            }
#pragma unroll
            for (int mt = 0; mt < 2; ++mt)
#pragma unroll
                for (int nt = 0; nt < 4; ++nt)
                    acc[mt][nt] = __builtin_amdgcn_mfma_f32_16x16x32_bf16(
                        af[mt], bf_[nt], acc[mt][nt], 0, 0, 0);
        }
    };

    int grow[2], gcb[2];
#pragma unroll
    for (int j = 0; j < 2; ++j) {
        int gi = j * 512 + tid;
        grow[j] = gi >> 3; gcb[j] = gi & 7;
    }
    f32x4 va[2], vb[2];
    auto loadA = [&](int kk) {
#pragma unroll
        for (int j = 0; j < 2; ++j) {
            const float* s = Af + (size_t)b * NN * NN
                           + (size_t)(m0 + grow[j]) * NN + kk * 64 + gcb[j] * 8;
            va[j] = *(const f32x4*)s;
            vb[j] = *(const f32x4*)(s + 4);
        }
    };
    auto writeA = [&](int buf, int kk) {
#pragma unroll
        for (int j = 0; j < 2; ++j) {
            bf16x8 o = {(bf16)va[j].x, (bf16)va[j].y, (bf16)va[j].z, (bf16)va[j].w,
                        (bf16)vb[j].x, (bf16)vb[j].y, (bf16)vb[j].z, (bf16)vb[j].w};
            int ch = grow[j] * 8 + (gcb[j] ^ (grow[j] & 7));
            *(bf16x8*)(lds + buf * 16384 + ch * 8) = o;
            *(bf16x8*)(Atl + (size_t)kk * 8192 + ch * 8) = o;
        }
    };
    loadA(0); stageB2(0, 0); writeA(0, 0);
    __syncthreads();
    int cur = 0;
    for (int kk = 0; kk < 32; ++kk) {
        if (kk < 31) { loadA(kk + 1); stageB2(cur ^ 1, kk + 1); }
        compute(cur);
        if (kk < 31) writeA(cur ^ 1, kk + 1);
        __syncthreads();
        cur ^= 1;
    }

    // epilogue (R3): G in LDS, W-GEMM from WTl, LN, tiled hOut write
    bf16* G = lds;
#pragma unroll
    for (int mt = 0; mt < 2; ++mt)
#pragma unroll
        for (int r = 0; r < 4; ++r) {
            int row = wm * 32 + mt * 16 + q * 4 + r;
#pragma unroll
            for (int nt = 0; nt < 4; ++nt) {
                int col = wn * 64 + nt * 16 + c0;
                G[row * 136 + col] = (bf16)acc[mt][nt][r];
            }
        }
    __syncthreads();

    f32x4 a2[8] = {};
    {
        const int gr = wave * 16 + c0;
#pragma unroll
        for (int ks = 0; ks < 4; ++ks) {
            bf16x8 af = *(const bf16x8*)(G + gr * 136 + ks * 32 + q * 8);
#pragma unroll
            for (int nt = 0; nt < 8; ++nt) {
                int n = nt * 16 + c0;
                int ch = n * 16 + (ks >> 1) * 8 + ((((ks & 1) << 2) | q) ^ (n & 7));
                bf16x8 bw = *(const bf16x8*)(WTl + ch * 8);
                a2[nt] = __builtin_amdgcn_mfma_f32_16x16x32_bf16(af, bw, a2[nt], 0, 0, 0);
            }
        }
    }

    float bv[8], gv[8], ev[8];
#pragma unroll
    for (int nt = 0; nt < 8; ++nt) {
        int n = nt * 16 + c0;
        bv[nt] = bias[n]; gv[nt] = gam[n]; ev[nt] = bet[n];
    }
    bf16* Cs = lds;
    __syncthreads();
#pragma unroll
    for (int r = 0; r < 4; ++r) {
        float v[8], s1 = 0.f, s2 = 0.f;
#pragma unroll
        for (int nt = 0; nt < 8; ++nt) {
            float xv = a2[nt][r] + bv[nt];
            v[nt] = xv; s1 += xv; s2 += xv * xv;
        }
#pragma unroll
        for (int off = 1; off < 16; off <<= 1) {
            s1 += __shfl_xor(s1, off);
            s2 += __shfl_xor(s2, off);
        }
        float mu = s1 * (1.f / 128.f);
        float var = s2 * (1.f / 128.f) - mu * mu;
        float rs = rsqrtf(var + 1e-5f);
        int row = wave * 16 + q * 4 + r;
#pragma unroll
        for (int nt = 0; nt < 8; ++nt) {
            float o = fmaxf((v[nt] - mu) * rs * gv[nt] + ev[nt], 0.f);
            Cs[(nt * 16 + c0) * 136 + row] = (bf16)o;
        }
    }
    __syncthreads();
#pragma unroll
    for (int i = 0; i < 4; ++i) {
        int p = i * 512 + tid;
        int half = p >> 10, p1 = p & 1023;
        int n = p1 >> 3, cs = p1 & 7, c = cs ^ (n & 7), m = half * 64 + c * 8;
        *(bf16x8*)(hOut + ((size_t)b * 32 + mtile * 2 + half) * 8192 + p1 * 8)
            = *(const bf16x8*)(Cs + n * 136 + m);
    }
}

// ---------------------------------------------------------------------------
// Layers 1/2: same tile geometry, QUAD-buffered, 4-phase fine interleave:
// per K-step {WAITV(8); barrier; 4x [issue 1 gload of tile kk+3; barrier;
// setprio(1) 4 MFMA setprio(0)]}.  Loads span phases (never drained mid-loop).
// W-frags from global in epilogue (R7-proven).
// ---------------------------------------------------------------------------
template<bool FINAL>
__global__ __launch_bounds__(512, 1) void layer8p(
        bf16* __restrict__ adjT, const bf16* __restrict__ Bt,
        const bf16* __restrict__ WTg,
        const float* __restrict__ bias, const float* __restrict__ gam,
        const float* __restrict__ bet, bf16* __restrict__ hOut,
        float* __restrict__ outF) {
    __shared__ __align__(16) bf16 lds[65536];   // 4 bufs x 16384 (A@0, B@8192)

    const int tid = threadIdx.x, wave = tid >> 6, lane = tid & 63;
    const int c0 = lane & 15, q = lane >> 4;
    const int blk = blockIdx.x, xcd = blk & 7, jj = blk >> 3;
    const int b = xcd * 2 + (jj & 1);
    const int mtile = jj >> 1, m0 = mtile * 128;
    const int wm = wave >> 1, wn = wave & 1;

    const bf16* Btb = Bt + (size_t)b * 32 * 8192;
    bf16* Atl = adjT + ((size_t)b * 16 + mtile) * (size_t)32 * 8192;

    f32x4 acc[2][4] = {};

    auto gA = [&](int p, int kk, int buf) {     // p in {0,1}: 512-chunk half
        int cb = p * 512 + wave * 64;
        gload_lds16(Atl + (size_t)kk * 8192 + (size_t)(cb + lane) * 8,
                    lds + buf * 16384 + cb * 8);
    };
    auto gB = [&](int p, int kk, int buf) {
        int cb = p * 512 + wave * 64;
        gload_lds16(Btb + (size_t)kk * 8192 + (size_t)(cb + lane) * 8,
                    lds + buf * 16384 + 8192 + cb * 8);
    };

    // prologue: tiles 0,1,2 fully staged (12 loads/wave in flight)
#pragma unroll
    for (int t = 0; t < 3; ++t) { gA(0, t, t); gA(1, t, t); gB(0, t, t); gB(1, t, t); }

#pragma unroll 1
    for (int kk = 0; kk < 32; ++kk) {
        const int buf = kk & 3, nb = (kk + 3) & 3;
        const bool pf = (kk < 29);
        // tile kk fully landed for this wave after the wait; barrier makes it
        // true for all waves' staged portions.
        if (kk <= 29)      WAITV(8);
        else if (kk == 30) WAITV(4);
        else               WAITV(0);
        __builtin_amdgcn_s_barrier();
        asm volatile("" ::: "memory");
        const bf16* As = lds + buf * 16384;
        const bf16* Bs = As + 8192;
#pragma unroll
        for (int ks = 0; ks < 2; ++ks) {
            bf16x8 af[2];
#pragma unroll
            for (int mt = 0; mt < 2; ++mt) {
                int row = wm * 32 + mt * 16 + c0;
                int cb = (ks * 4 + q) ^ (row & 7);
                af[mt] = *(const bf16x8*)(As + row * 64 + cb * 8);
            }
#pragma unroll
            for (int half = 0; half < 2; ++half) {
                // phase: issue ONE next-tile load, then a 4-MFMA cluster
                if (pf) {
                    if (ks == 0) gA(half, kk + 3, nb);
                    else         gB(half, kk + 3, nb);
                }
                __builtin_amdgcn_s_barrier();
                bf16x8 bf_[2];
#pragma unroll
                for (int j = 0; j < 2; ++j) {
                    int nt = half * 2 + j;
                    int row = wn * 64 + nt * 16 + c0;
                    int cb = (ks * 4 + q) ^ (row & 7);
                    bf_[j] = *(const bf16x8*)(Bs + row * 64 + cb * 8);
                }
                __builtin_amdgcn_s_setprio(1);
#pragma unroll
                for (int mt = 0; mt < 2; ++mt)
#pragma unroll
                    for (int j = 0; j < 2; ++j)
                        acc[mt][half * 2 + j] = __builtin_amdgcn_mfma_f32_16x16x32_bf16(
                            af[mt], bf_[j], acc[mt][half * 2 + j], 0, 0, 0);
                __builtin_amdgcn_s_setprio(0);
            }
        }
        asm volatile("" ::: "memory");
    }
    __syncthreads();    // all compute done; buffers dead

    // ---- epilogue (R7-proven): G in LDS, W-frags from global ----
    bf16* G = lds;
#pragma unroll
    for (int mt = 0; mt < 2; ++mt)
#pragma unroll
        for (int r = 0; r < 4; ++r) {
            int row = wm * 32 + mt * 16 + q * 4 + r;
#pragma unroll
            for (int nt = 0; nt < 4; ++nt) {
                int col = wn * 64 + nt * 16 + c0;
                G[row * 136 + col] = (bf16)acc[mt][nt][r];
            }
        }
    __syncthreads();

    f32x4 a2[8] = {};
    {
        const int gr = wave * 16 + c0;
#pragma unroll
        for (int ks = 0; ks < 4; ++ks) {
            bf16x8 af = *(const bf16x8*)(G + gr * 136 + ks * 32 + q * 8);
#pragma unroll
            for (int nt = 0; nt < 8; ++nt) {
                int n = nt * 16 + c0;
                int ch = n * 16 + (ks >> 1) * 8 + ((((ks & 1) << 2) | q) ^ (n & 7));
                bf16x8 bw = *(const bf16x8*)(WTg + (size_t)ch * 8);
                a2[nt] = __builtin_amdgcn_mfma_f32_16x16x32_bf16(af, bw, a2[nt], 0, 0, 0);
            }
        }
    }

    float bv[8], gv[8], ev[8];
#pragma unroll
    for (int nt = 0; nt < 8; ++nt) {
        int n = nt * 16 + c0;
        bv[nt] = bias[n]; gv[nt] = gam[n]; ev[nt] = bet[n];
    }
    bf16* Cs = lds;
    if constexpr (!FINAL) __syncthreads();
#pragma unroll
    for (int r = 0; r < 4; ++r) {
        float v[8], s1 = 0.f, s2 = 0.f;
#pragma unroll
        for (int nt = 0; nt < 8; ++nt) {
            float xv = a2[nt][r] + bv[nt];
            v[nt] = xv; s1 += xv; s2 += xv * xv;
        }
#pragma unroll
        for (int off = 1; off < 16; off <<= 1) {
            s1 += __shfl_xor(s1, off);
            s2 += __shfl_xor(s2, off);
        }
        float mu = s1 * (1.f / 128.f);
        float var = s2 * (1.f / 128.f) - mu * mu;
        float rs = rsqrtf(var + 1e-5f);
        int row = wave * 16 + q * 4 + r;
        if constexpr (FINAL) {
            size_t ro = ((size_t)b * NN + m0 + row) * HID;
#pragma unroll
            for (int nt = 0; nt < 8; ++nt) {
                float o = fmaxf((v[nt] - mu) * rs * gv[nt] + ev[nt], 0.f);
                outF[ro + nt * 16 + c0] = o;
            }
        } else {
#pragma unroll
            for (int nt = 0; nt < 8; ++nt) {
                float o = fmaxf((v[nt] - mu) * rs * gv[nt] + ev[nt], 0.f);
                Cs[(nt * 16 + c0) * 136 + row] = (bf16)o;
            }
        }
    }
    if constexpr (!FINAL) {
        __syncthreads();
#pragma unroll
        for (int i = 0; i < 4; ++i) {
            int p = i * 512 + tid;
            int half = p >> 10, p1 = p & 1023;
            int n = p1 >> 3, cs = p1 & 7, c = cs ^ (n & 7), m = half * 64 + c * 8;
            *(bf16x8*)(hOut + ((size_t)b * 32 + mtile * 2 + half) * 8192 + p1 * 8)
                = *(const bf16x8*)(Cs + n * 136 + m);
        }
    }
}

// ---------------------------------------------------------------------------
extern "C" void kernel_launch(void* const* d_in, const int* in_sizes, int n_in,
                              void* d_out, int out_size, void* d_ws, size_t ws_size,
                              hipStream_t stream) {
    const float* x   = (const float*)d_in[0];
    const float* adj = (const float*)d_in[1];
    const float* W[3]  = {(const float*)d_in[2],  (const float*)d_in[6],  (const float*)d_in[10]};
    const float* bb[3] = {(const float*)d_in[3],  (const float*)d_in[7],  (const float*)d_in[11]};
    const float* gg[3] = {(const float*)d_in[4],  (const float*)d_in[8],  (const float*)d_in[12]};
    const float* be[3] = {(const float*)d_in[5],  (const float*)d_in[9],  (const float*)d_in[13]};

    char* ws = (char*)d_ws;
    size_t off = 0;
    auto alloc = [&](size_t bytes) {
        char* p = ws + off; off = (off + bytes + 255) & ~(size_t)255; return p;
    };
    bf16* WTg  = (bf16*)alloc((size_t)3 * 16384 * 2);
    bf16* xTt  = (bf16*)alloc((size_t)NB * 32 * 8192 * 2);        // 8 MiB
    bf16* hT0  = (bf16*)alloc((size_t)NB * 32 * 8192 * 2);        // 8 MiB
    bf16* hT1  = (bf16*)alloc((size_t)NB * 32 * 8192 * 2);        // 8 MiB
    bf16* adjT = (bf16*)alloc((size_t)NB * 16 * 32 * 8192 * 2);   // 128 MiB

    float* outF = (float*)d_out;

    prep_wt<<<3, 256, 0, stream>>>(W[0], W[1], W[2], WTg);
    prep_xt<<<256, 256, 0, stream>>>(x, xTt);

    layer0<<<256, 512, 0, stream>>>(adj, adjT, xTt, WTg,
                                    bb[0], gg[0], be[0], hT0);
    layer8p<false><<<256, 512, 0, stream>>>(adjT, hT0, WTg + 16384,
                                            bb[1], gg[1], be[1], hT1, nullptr);
    layer8p<true ><<<256, 512, 0, stream>>>(adjT, hT1, WTg + 2 * 16384,
                                            bb[2], gg[2], be[2], nullptr, outF);
}

// Round 10
// 497.632 us; speedup vs baseline: 1.1056x; 1.0069x over previous
//
#include <hip/hip_runtime.h>
#include <hip/hip_bf16.h>

typedef __bf16 bf16;
typedef __bf16 bf16x8 __attribute__((ext_vector_type(8)));
typedef float  f32x4  __attribute__((ext_vector_type(4)));

static constexpr int NB  = 16;
static constexpr int NN  = 2048;
static constexpr int HID = 128;

// async 16B global -> LDS. LDS dest is wave-uniform base (+ lane*16 in HW);
// global src address IS per-lane (must carry the lane term!).
__device__ __forceinline__ void gload_lds16(const bf16* g, bf16* l) {
    __builtin_amdgcn_global_load_lds(
        (const __attribute__((address_space(1))) unsigned int*)g,
        (__attribute__((address_space(3))) unsigned int*)l, 16, 0, 0);
}

// ---------------------------------------------------------------------------
// Tiled layouts ("LDS images", 16 KB tiles of 1024 16B-chunks):
//   A-tile (128 rows x 64 k): chunk p = row*8 + (kc ^ (row&7)), kc = k/8
//   B-tile (128 n   x 64 k): same formula with n as row
//   adjT[b][mtile(16)][kk(32)] tiles ; xTt/hT: [b][kk(32)] tiles
//   A BK=128 step t uses tiles {2t, 2t+1} = 32 KB CONTIGUOUS in both
//   adjT and xTt/hT -> staging is a pure linear copy; writers unchanged.
//   WTg per layer: 2048 chunks: chunk = n*16 + half*8 + (kc8 ^ (n&7)),
//     half = k>>6, kc8 = (k&63)>>3  (k-contig bf16x8 fragments of W^T[n][k])
// ---------------------------------------------------------------------------

// prep: W (128x128 fp32, [k][n]) -> swizzled WT tiles, for all 3 layers
__global__ __launch_bounds__(256) void prep_wt(const float* __restrict__ W0,
                                               const float* __restrict__ W1,
                                               const float* __restrict__ W2,
                                               bf16* __restrict__ WTg) {
    int l = blockIdx.x;
    const float* W = (l == 0) ? W0 : (l == 1) ? W1 : W2;
    bf16* out = WTg + l * 16384;
    int tid = threadIdx.x;
#pragma unroll
    for (int i = 0; i < 8; ++i) {
        int p = i * 256 + tid;                 // [0,2048)
        int n = p >> 4, half = (p >> 3) & 1, cs = p & 7;
        int kc = cs ^ (n & 7);
        int kbase = half * 64 + kc * 8;
        bf16x8 o;
#pragma unroll
        for (int r = 0; r < 8; ++r) o[r] = (bf16)W[(kbase + r) * 128 + n];
        *(bf16x8*)(out + p * 8) = o;
    }
}

// prep: x (16,2048,128) fp32 -> xTt tiled bf16 B-tiles
__global__ __launch_bounds__(256) void prep_xt(const float* __restrict__ x,
                                               bf16* __restrict__ xTt) {
    __shared__ bf16 T[128 * 136];
    const int blk = blockIdx.x;            // 256 blocks: 16 node-tiles x 16 b
    const int b = blk >> 4, node0 = (blk & 15) * 128;
    const int tid = threadIdx.x;
    const float* xb = x + ((size_t)b * NN + node0) * HID;
#pragma unroll
    for (int i = 0; i < 64; ++i) {
        int idx = i * 256 + tid;
        int node = idx >> 7, hid = idx & 127;
        T[hid * 136 + node] = (bf16)xb[(size_t)node * HID + hid];
    }
    __syncthreads();
#pragma unroll
    for (int i = 0; i < 8; ++i) {
        int p = i * 256 + tid;                 // [0,2048) chunks (2 tiles)
        int half = p >> 10, p1 = p & 1023;
        int n = p1 >> 3, cs = p1 & 7, c = cs ^ (n & 7), m = half * 64 + c * 8;
        *(bf16x8*)(xTt + ((size_t)b * 32 + (node0 >> 6) + half) * 8192 + p1 * 8)
            = *(const bf16x8*)(T + n * 136 + m);
    }
}

// ---------------------------------------------------------------------------
// Shared epilogue: G(128x128 bf16, LDS [128][136]) @ W (frags from global,
// L2-resident) + bias + LN + ReLU -> tiled hOut or fp32 outF.  R7-proven.
// ---------------------------------------------------------------------------
template<bool FINAL>
__device__ __forceinline__ void epilogue(
        bf16* lds, const f32x4 (&acc)[2][4],
        const bf16* __restrict__ WTg,
        const float* __restrict__ bias, const float* __restrict__ gam,
        const float* __restrict__ bet, bf16* __restrict__ hOut,
        float* __restrict__ outF, int b, int mtile, int m0) {
    const int tid = threadIdx.x, wave = tid >> 6, lane = tid & 63;
    const int c0 = lane & 15, q = lane >> 4;
    const int wm = wave >> 1, wn = wave & 1;

    bf16* G = lds;
#pragma unroll
    for (int mt = 0; mt < 2; ++mt)
#pragma unroll
        for (int r = 0; r < 4; ++r) {
            int row = wm * 32 + mt * 16 + q * 4 + r;
#pragma unroll
            for (int nt = 0; nt < 4; ++nt) {
                int col = wn * 64 + nt * 16 + c0;
                G[row * 136 + col] = (bf16)acc[mt][nt][r];
            }
        }
    __syncthreads();

    f32x4 a2[8] = {};
    {
        const int gr = wave * 16 + c0;
#pragma unroll
        for (int ks = 0; ks < 4; ++ks) {
            bf16x8 af = *(const bf16x8*)(G + gr * 136 + ks * 32 + q * 8);
#pragma unroll
            for (int nt = 0; nt < 8; ++nt) {
                int n = nt * 16 + c0;
                int ch = n * 16 + (ks >> 1) * 8 + ((((ks & 1) << 2) | q) ^ (n & 7));
                bf16x8 bw = *(const bf16x8*)(WTg + (size_t)ch * 8);
                a2[nt] = __builtin_amdgcn_mfma_f32_16x16x32_bf16(af, bw, a2[nt], 0, 0, 0);
            }
        }
    }

    float bv[8], gv[8], ev[8];
#pragma unroll
    for (int nt = 0; nt < 8; ++nt) {
        int n = nt * 16 + c0;
        bv[nt] = bias[n]; gv[nt] = gam[n]; ev[nt] = bet[n];
    }
    bf16* Cs = lds;
    if constexpr (!FINAL) __syncthreads();   // all W-GEMM reads of G done
#pragma unroll
    for (int r = 0; r < 4; ++r) {
        float v[8], s1 = 0.f, s2 = 0.f;
#pragma unroll
        for (int nt = 0; nt < 8; ++nt) {
            float xv = a2[nt][r] + bv[nt];
            v[nt] = xv; s1 += xv; s2 += xv * xv;
        }
#pragma unroll
        for (int off = 1; off < 16; off <<= 1) {
            s1 += __shfl_xor(s1, off);
            s2 += __shfl_xor(s2, off);
        }
        float mu = s1 * (1.f / 128.f);
        float var = s2 * (1.f / 128.f) - mu * mu;
        float rs = rsqrtf(var + 1e-5f);
        int row = wave * 16 + q * 4 + r;      // local row in [0,128)
        if constexpr (FINAL) {
            size_t ro = ((size_t)b * NN + m0 + row) * HID;
#pragma unroll
            for (int nt = 0; nt < 8; ++nt) {
                float o = fmaxf((v[nt] - mu) * rs * gv[nt] + ev[nt], 0.f);
                outF[ro + nt * 16 + c0] = o;
            }
        } else {
#pragma unroll
            for (int nt = 0; nt < 8; ++nt) {
                float o = fmaxf((v[nt] - mu) * rs * gv[nt] + ev[nt], 0.f);
                Cs[(nt * 16 + c0) * 136 + row] = (bf16)o;
            }
        }
    }
    if constexpr (!FINAL) {
        __syncthreads();
        // write 2 tiled B-tiles (kk = mtile*2, mtile*2+1), fully linear
#pragma unroll
        for (int i = 0; i < 4; ++i) {
            int p = i * 512 + tid;            // [0,2048)
            int half = p >> 10, p1 = p & 1023;
            int n = p1 >> 3, cs = p1 & 7, c = cs ^ (n & 7), m = half * 64 + c * 8;
            *(bf16x8*)(hOut + ((size_t)b * 32 + mtile * 2 + half) * 8192 + p1 * 8)
                = *(const bf16x8*)(Cs + n * 136 + m);
        }
    }
}

// ---------------------------------------------------------------------------
// Layer 0: BK=128 (16 K-steps), 8 waves, 2-deep __syncthreads pipeline.
// A from fp32 adj (512B/row contiguous segs) -> regs -> cvt -> LDS + tiled
// adjT side-write.  B staged as linear 32 KB (2 consecutive tiles).
// LDS: 2 bufs x (A 32 KB + B 32 KB) = 128 KB.
// ---------------------------------------------------------------------------
__global__ __launch_bounds__(512, 1) void layer0(
        const float* __restrict__ Af, bf16* __restrict__ adjT,
        const bf16* __restrict__ Bt, const bf16* __restrict__ WTg,
        const float* __restrict__ bias, const float* __restrict__ gam,
        const float* __restrict__ bet, bf16* __restrict__ hOut) {
    __shared__ __align__(16) bf16 lds[65536];   // 2 x 32768 (A 16384 + B 16384)

    const int tid = threadIdx.x, wave = tid >> 6, lane = tid & 63;
    const int c0 = lane & 15, q = lane >> 4;
    const int blk = blockIdx.x, xcd = blk & 7, jj = blk >> 3;
    const int b = xcd * 2 + (jj & 1);
    const int mtile = jj >> 1, m0 = mtile * 128;
    const int wm = wave >> 1, wn = wave & 1;

    const bf16* Btb = Bt + (size_t)b * 32 * 8192;
    bf16* Atl = adjT + ((size_t)b * 16 + mtile) * (size_t)32 * 8192;

    f32x4 acc[2][4] = {};

    auto stageB = [&](int buf, int t) {      // 2048 chunks linear: 4/wave
#pragma unroll
        for (int j = 0; j < 4; ++j) {
            int cb = j * 512 + wave * 64;
            gload_lds16(Btb + (size_t)t * 16384 + (size_t)(cb + lane) * 8,
                        lds + buf * 32768 + 16384 + cb * 8);
        }
    };
    auto compute = [&](int buf) {
        const bf16* As = lds + buf * 32768;
        const bf16* Bs = As + 16384;
#pragma unroll
        for (int T = 0; T < 2; ++T)          // tile even/odd within the step
#pragma unroll
            for (int ks = 0; ks < 2; ++ks) {
                bf16x8 af[2], bf_[4];
#pragma unroll
                for (int mt = 0; mt < 2; ++mt) {
                    int row = wm * 32 + mt * 16 + c0;
                    int cb = (ks * 4 + q) ^ (row & 7);
                    af[mt] = *(const bf16x8*)(As + T * 8192 + row * 64 + cb * 8);
                }
#pragma unroll
                for (int nt = 0; nt < 4; ++nt) {
                    int row = wn * 64 + nt * 16 + c0;
                    int cb = (ks * 4 + q) ^ (row & 7);
                    bf_[nt] = *(const bf16x8*)(Bs + T * 8192 + row * 64 + cb * 8);
                }
#pragma unroll
                for (int mt = 0; mt < 2; ++mt)
#pragma unroll
                    for (int nt = 0; nt < 4; ++nt)
                        acc[mt][nt] = __builtin_amdgcn_mfma_f32_16x16x32_bf16(
                            af[mt], bf_[nt], acc[mt][nt], 0, 0, 0);
            }
    };

    // A: per thread 4 chunks (8-float) of the 128x128 fp32 step-slab
    int g_row[4], g_cc[4];
#pragma unroll
    for (int j = 0; j < 4; ++j) {
        int gi = j * 512 + tid;
        g_row[j] = gi >> 4; g_cc[j] = gi & 15;   // row [0,128), chunk-col [0,16)
    }
    f32x4 va[4], vb[4];
    auto loadA = [&](int t) {
#pragma unroll
        for (int j = 0; j < 4; ++j) {
            const float* s = Af + (size_t)b * NN * NN
                           + (size_t)(m0 + g_row[j]) * NN + t * 128 + g_cc[j] * 8;
            va[j] = *(const f32x4*)s;
            vb[j] = *(const f32x4*)(s + 4);
        }
    };
    auto writeA = [&](int buf, int t) {
#pragma unroll
        for (int j = 0; j < 4; ++j) {
            bf16x8 o = {(bf16)va[j].x, (bf16)va[j].y, (bf16)va[j].z, (bf16)va[j].w,
                        (bf16)vb[j].x, (bf16)vb[j].y, (bf16)vb[j].z, (bf16)vb[j].w};
            int tile = g_cc[j] >> 3, kc = g_cc[j] & 7;
            int ch = g_row[j] * 8 + (kc ^ (g_row[j] & 7));
            *(bf16x8*)(lds + buf * 32768 + tile * 8192 + ch * 8) = o;
            *(bf16x8*)(Atl + (size_t)t * 16384 + (size_t)tile * 8192 + ch * 8) = o;
        }
    };

    loadA(0); stageB(0, 0); writeA(0, 0);
    __syncthreads();
    int cur = 0;
    for (int t = 0; t < 16; ++t) {
        if (t < 15) { loadA(t + 1); stageB(cur ^ 1, t + 1); }
        compute(cur);
        if (t < 15) writeA(cur ^ 1, t + 1);
        __syncthreads();
        cur ^= 1;
    }

    epilogue<false>(lds, acc, WTg, bias, gam, bet, hOut, nullptr, b, mtile, m0);
}

// ---------------------------------------------------------------------------
// Layers 1/2: BK=128 (16 K-steps), A+B both via linear 32 KB gload_lds,
// R3-proven drain-per-step schedule.
// ---------------------------------------------------------------------------
template<bool FINAL>
__global__ __launch_bounds__(512, 1) void layerK(
        const bf16* __restrict__ adjT, const bf16* __restrict__ Bt,
        const bf16* __restrict__ WTg,
        const float* __restrict__ bias, const float* __restrict__ gam,
        const float* __restrict__ bet, bf16* __restrict__ hOut,
        float* __restrict__ outF) {
    __shared__ __align__(16) bf16 lds[65536];   // 2 x 32768 (A 16384 + B 16384)

    const int tid = threadIdx.x, wave = tid >> 6, lane = tid & 63;
    const int c0 = lane & 15, q = lane >> 4;
    const int blk = blockIdx.x, xcd = blk & 7, jj = blk >> 3;
    const int b = xcd * 2 + (jj & 1);
    const int mtile = jj >> 1, m0 = mtile * 128;
    const int wm = wave >> 1, wn = wave & 1;

    const bf16* Btb = Bt + (size_t)b * 32 * 8192;
    const bf16* Atl = adjT + ((size_t)b * 16 + mtile) * (size_t)32 * 8192;

    f32x4 acc[2][4] = {};

    auto stageA = [&](int buf, int t) {      // 2048 chunks linear: 4/wave
#pragma unroll
        for (int j = 0; j < 4; ++j) {
            int cb = j * 512 + wave * 64;
            gload_lds16(Atl + (size_t)t * 16384 + (size_t)(cb + lane) * 8,
                        lds + buf * 32768 + cb * 8);
        }
    };
    auto stageB = [&](int buf, int t) {
#pragma unroll
        for (int j = 0; j < 4; ++j) {
            int cb = j * 512 + wave * 64;
            gload_lds16(Btb + (size_t)t * 16384 + (size_t)(cb + lane) * 8,
                        lds + buf * 32768 + 16384 + cb * 8);
        }
    };
    auto compute = [&](int buf) {
        const bf16* As = lds + buf * 32768;
        const bf16* Bs = As + 16384;
#pragma unroll
        for (int T = 0; T < 2; ++T)
#pragma unroll
            for (int ks = 0; ks < 2; ++ks) {
                bf16x8 af[2], bf_[4];
#pragma unroll
                for (int mt = 0; mt < 2; ++mt) {
                    int row = wm * 32 + mt * 16 + c0;
                    int cb = (ks * 4 + q) ^ (row & 7);
                    af[mt] = *(const bf16x8*)(As + T * 8192 + row * 64 + cb * 8);
                }
#pragma unroll
                for (int nt = 0; nt < 4; ++nt) {
                    int row = wn * 64 + nt * 16 + c0;
                    int cb = (ks * 4 + q) ^ (row & 7);
                    bf_[nt] = *(const bf16x8*)(Bs + T * 8192 + row * 64 + cb * 8);
                }
#pragma unroll
                for (int mt = 0; mt < 2; ++mt)
#pragma unroll
                    for (int nt = 0; nt < 4; ++nt)
                        acc[mt][nt] = __builtin_amdgcn_mfma_f32_16x16x32_bf16(
                            af[mt], bf_[nt], acc[mt][nt], 0, 0, 0);
            }
    };

    stageA(0, 0); stageB(0, 0);
    __syncthreads();
    int cur = 0;
    for (int t = 0; t < 16; ++t) {
        if (t < 15) { stageA(cur ^ 1, t + 1); stageB(cur ^ 1, t + 1); }
        compute(cur);
        __syncthreads();
        cur ^= 1;
    }

    epilogue<FINAL>(lds, acc, WTg, bias, gam, bet, hOut, outF, b, mtile, m0);
}

// ---------------------------------------------------------------------------
extern "C" void kernel_launch(void* const* d_in, const int* in_sizes, int n_in,
                              void* d_out, int out_size, void* d_ws, size_t ws_size,
                              hipStream_t stream) {
    const float* x   = (const float*)d_in[0];
    const float* adj = (const float*)d_in[1];
    const float* W[3]  = {(const float*)d_in[2],  (const float*)d_in[6],  (const float*)d_in[10]};
    const float* bb[3] = {(const float*)d_in[3],  (const float*)d_in[7],  (const float*)d_in[11]};
    const float* gg[3] = {(const float*)d_in[4],  (const float*)d_in[8],  (const float*)d_in[12]};
    const float* be[3] = {(const float*)d_in[5],  (const float*)d_in[9],  (const float*)d_in[13]};

    char* ws = (char*)d_ws;
    size_t off = 0;
    auto alloc = [&](size_t bytes) {
        char* p = ws + off; off = (off + bytes + 255) & ~(size_t)255; return p;
    };
    bf16* WTg  = (bf16*)alloc((size_t)3 * 16384 * 2);
    bf16* xTt  = (bf16*)alloc((size_t)NB * 32 * 8192 * 2);        // 8 MiB
    bf16* hT0  = (bf16*)alloc((size_t)NB * 32 * 8192 * 2);        // 8 MiB
    bf16* hT1  = (bf16*)alloc((size_t)NB * 32 * 8192 * 2);        // 8 MiB
    bf16* adjT = (bf16*)alloc((size_t)NB * 16 * 32 * 8192 * 2);   // 128 MiB

    float* outF = (float*)d_out;

    prep_wt<<<3, 256, 0, stream>>>(W[0], W[1], W[2], WTg);
    prep_xt<<<256, 256, 0, stream>>>(x, xTt);

    layer0<<<256, 512, 0, stream>>>(adj, adjT, xTt, WTg,
                                    bb[0], gg[0], be[0], hT0);
    layerK<false><<<256, 512, 0, stream>>>(adjT, hT0, WTg + 16384,
                                           bb[1], gg[1], be[1], hT1, nullptr);
    layerK<true ><<<256, 512, 0, stream>>>(adjT, hT1, WTg + 2 * 16384,
                                           bb[2], gg[2], be[2], nullptr, outF);
}